// Round 7
// baseline (410.008 us; speedup 1.0000x reference)
//
#include <hip/hip_runtime.h>

// VQ-VAE quantizer — round 16: the ENTIRE main loop in ONE asm block,
// physical registers for codebook (v[64:127]) and z row (s[36:99]).
// Inputs fp32: z_e [32,64,64,64], codebook [512,64].
// Output fp32: z_q [8388608] ++ indices-as-float [131072].
//
// Reference (np, fp32): d = rn( rn(s1 + s2[k]) - 2*M32[k] ), argmin ties->lowest.
//   M32 chain: c-ascending single-accumulator fma — v_fmac_f32 IS rn(S0*S1+D).
//   d: v_fma_f32 v40, v40, -2.0, T == rn(T - 2*M) (2M exact, inline const).
//   argmin: exact value-min butterfly (min is exact), then v_cmp_eq + s_ff1
//   -> lowest equal lane -> lowest k. Cross-wave merge ascending w, strict <.
//   All bit-identical to R13 (passed, absmax 0).
//
// R10-R15 post-mortem: the allocator homes EVERY compiler-visible long-lived
// 64-float array in AGPRs and materializes ~1 copy op per fma use; per-use
// asm constraints ("v") just turn homing into per-use v_accvgpr_read, and
// clobber lists can't reserve registers BETWEEN asm statements. Only a single
// asm block owning the whole loop removes the allocator from the picture.

typedef __attribute__((ext_vector_type(4))) float fl4;

// ---------- kernel A: z -> z_t[n][64] (row-contiguous) + s1[n] ----------
// (verbatim R13a/R15a — proven; ~10-16us implied)
__global__ __launch_bounds__(256)
void vq16a(const float* __restrict__ z, float* __restrict__ ow)
{
    __shared__ float zl[256][65];              // +1 dword pad: conflict-free
    const int tid = threadIdx.x;
    const int n0  = blockIdx.x << 8;           // 512 blocks x 256 samples
    const int n   = n0 + tid;
    const size_t base = (size_t)(n >> 12) * 262144 + (size_t)(n & 4095);

    float p[8];
    #pragma unroll
    for (int c = 0; c < 64; ++c) {
        const float v = z[base + (size_t)c * 4096];   // coalesced across tid
        zl[tid][c] = v;
        const float sq = __fmul_rn(v, v);             // np: z**2 rounds first
        if (c < 8) p[c] = sq;
        else       p[c & 7] = __fadd_rn(p[c & 7], sq);
    }
    const float s1 = __fadd_rn(__fadd_rn(__fadd_rn(p[0],p[1]),__fadd_rn(p[2],p[3])),
                               __fadd_rn(__fadd_rn(p[4],p[5]),__fadd_rn(p[6],p[7])));
    ow[8388608 + n] = s1;                             // s1 -> indices region
    __syncthreads();

    float* zt = ow + (size_t)n0 * 64;
    #pragma unroll
    for (int j = 0; j < 16; ++j) {
        const int f  = j * 256 + tid;
        const int nl = f >> 4, c0 = (f & 15) << 2;
        fl4 v;
        #pragma unroll
        for (int e = 0; e < 4; ++e) v[e] = zl[nl][c0 + e];
        *(fl4*)(zt + ((size_t)f << 2)) = v;
    }
}

// ---------- kernel B: lane=code, whole main loop in one asm block ----------
__global__ __launch_bounds__(512)
void vq16b(const float* __restrict__ cb,
           const float* __restrict__ zt,      // == ow (z_q region)
           const float* __restrict__ s1g,     // == ow + 8388608
           float* __restrict__ ow)
{
    __shared__ float s1l[128];
    __shared__ float cdl[8][128];             // per-wave candidate d
    __shared__ int   ckl[8][128];             // per-wave candidate k
    __shared__ int   ifin[128];

    const int tid  = threadIdx.x;
    const int w    = tid >> 6;                // wave 0..7
    const int lane = tid & 63;
    const int n0   = blockIdx.x << 7;         // 1024 blocks x 128 samples
    const int k    = (w << 6) + lane;         // this lane's code

    // s2 for this code (np order) from a SHORT-LIVED load (dies before asm)
    float s2k;
    {
        const float* row = cb + ((size_t)k << 6);
        float q[8];
        #pragma unroll
        for (int j = 0; j < 8; ++j) q[j] = __fmul_rn(row[j], row[j]);
        #pragma unroll
        for (int m = 1; m < 8; ++m)
            #pragma unroll
            for (int j = 0; j < 8; ++j)
                q[j] = __fadd_rn(q[j], __fmul_rn(row[m*8+j], row[m*8+j]));
        s2k = __fadd_rn(__fadd_rn(__fadd_rn(q[0],q[1]),__fadd_rn(q[2],q[3])),
                        __fadd_rn(__fadd_rn(q[4],q[5]),__fadd_rn(q[6],q[7])));
    }

    if (tid < 128) s1l[tid] = s1g[n0 + tid];  // read BEFORE overwrite
    __syncthreads();

    // asm operands
    const float* cbrow = cb + ((size_t)k << 6);          // lane-varying, 16B aligned
    const float* zrow  = zt + ((size_t)n0 << 6);         // uniform -> SGPR pair
    unsigned s1a = (unsigned)(unsigned long long)&s1l[0];        // LDS offsets
    unsigned cda = (unsigned)(unsigned long long)&cdl[w][0];
    unsigned cka = (unsigned)(unsigned long long)&ckl[w][0];
    const int x32a  = (lane ^ 32) << 2;                  // bpermute addr
    const int wbase = w << 6;                            // lane-uniform, kept in VGPR

    asm volatile(
        // ---- codebook row -> v[64:127], once ----
        "global_load_dwordx4 v[64:67],   %[cbr], off\n\t"
        "global_load_dwordx4 v[68:71],   %[cbr], off offset:16\n\t"
        "global_load_dwordx4 v[72:75],   %[cbr], off offset:32\n\t"
        "global_load_dwordx4 v[76:79],   %[cbr], off offset:48\n\t"
        "global_load_dwordx4 v[80:83],   %[cbr], off offset:64\n\t"
        "global_load_dwordx4 v[84:87],   %[cbr], off offset:80\n\t"
        "global_load_dwordx4 v[88:91],   %[cbr], off offset:96\n\t"
        "global_load_dwordx4 v[92:95],   %[cbr], off offset:112\n\t"
        "global_load_dwordx4 v[96:99],   %[cbr], off offset:128\n\t"
        "global_load_dwordx4 v[100:103], %[cbr], off offset:144\n\t"
        "global_load_dwordx4 v[104:107], %[cbr], off offset:160\n\t"
        "global_load_dwordx4 v[108:111], %[cbr], off offset:176\n\t"
        "global_load_dwordx4 v[112:115], %[cbr], off offset:192\n\t"
        "global_load_dwordx4 v[116:119], %[cbr], off offset:208\n\t"
        "global_load_dwordx4 v[120:123], %[cbr], off offset:224\n\t"
        "global_load_dwordx4 v[124:127], %[cbr], off offset:240\n\t"
        "s_mov_b64 s[34:35], %[zrow]\n\t"
        "s_movk_i32 s26, 0x80\n\t"
        "s_waitcnt vmcnt(0)\n\t"
        // ---- 128-sample loop ----
        "1:\n\t"
        "s_load_dwordx16 s[36:51], s[34:35], 0x0\n\t"
        "s_load_dwordx16 s[52:67], s[34:35], 0x40\n\t"
        "s_load_dwordx16 s[68:83], s[34:35], 0x80\n\t"
        "s_load_dwordx16 s[84:99], s[34:35], 0xC0\n\t"
        "ds_read_b32 v41, %[s1a]\n\t"
        "v_mov_b32 v40, 0\n\t"
        "s_waitcnt lgkmcnt(0)\n\t"
        // 64-step c-ascending single-accumulator chain: the reference grid
        "v_fmac_f32 v40, s36, v64\n\t"  "v_fmac_f32 v40, s37, v65\n\t"
        "v_fmac_f32 v40, s38, v66\n\t"  "v_fmac_f32 v40, s39, v67\n\t"
        "v_fmac_f32 v40, s40, v68\n\t"  "v_fmac_f32 v40, s41, v69\n\t"
        "v_fmac_f32 v40, s42, v70\n\t"  "v_fmac_f32 v40, s43, v71\n\t"
        "v_fmac_f32 v40, s44, v72\n\t"  "v_fmac_f32 v40, s45, v73\n\t"
        "v_fmac_f32 v40, s46, v74\n\t"  "v_fmac_f32 v40, s47, v75\n\t"
        "v_fmac_f32 v40, s48, v76\n\t"  "v_fmac_f32 v40, s49, v77\n\t"
        "v_fmac_f32 v40, s50, v78\n\t"  "v_fmac_f32 v40, s51, v79\n\t"
        "v_fmac_f32 v40, s52, v80\n\t"  "v_fmac_f32 v40, s53, v81\n\t"
        "v_fmac_f32 v40, s54, v82\n\t"  "v_fmac_f32 v40, s55, v83\n\t"
        "v_fmac_f32 v40, s56, v84\n\t"  "v_fmac_f32 v40, s57, v85\n\t"
        "v_fmac_f32 v40, s58, v86\n\t"  "v_fmac_f32 v40, s59, v87\n\t"
        "v_fmac_f32 v40, s60, v88\n\t"  "v_fmac_f32 v40, s61, v89\n\t"
        "v_fmac_f32 v40, s62, v90\n\t"  "v_fmac_f32 v40, s63, v91\n\t"
        "v_fmac_f32 v40, s64, v92\n\t"  "v_fmac_f32 v40, s65, v93\n\t"
        "v_fmac_f32 v40, s66, v94\n\t"  "v_fmac_f32 v40, s67, v95\n\t"
        "v_fmac_f32 v40, s68, v96\n\t"  "v_fmac_f32 v40, s69, v97\n\t"
        "v_fmac_f32 v40, s70, v98\n\t"  "v_fmac_f32 v40, s71, v99\n\t"
        "v_fmac_f32 v40, s72, v100\n\t" "v_fmac_f32 v40, s73, v101\n\t"
        "v_fmac_f32 v40, s74, v102\n\t" "v_fmac_f32 v40, s75, v103\n\t"
        "v_fmac_f32 v40, s76, v104\n\t" "v_fmac_f32 v40, s77, v105\n\t"
        "v_fmac_f32 v40, s78, v106\n\t" "v_fmac_f32 v40, s79, v107\n\t"
        "v_fmac_f32 v40, s80, v108\n\t" "v_fmac_f32 v40, s81, v109\n\t"
        "v_fmac_f32 v40, s82, v110\n\t" "v_fmac_f32 v40, s83, v111\n\t"
        "v_fmac_f32 v40, s84, v112\n\t" "v_fmac_f32 v40, s85, v113\n\t"
        "v_fmac_f32 v40, s86, v114\n\t" "v_fmac_f32 v40, s87, v115\n\t"
        "v_fmac_f32 v40, s88, v116\n\t" "v_fmac_f32 v40, s89, v117\n\t"
        "v_fmac_f32 v40, s90, v118\n\t" "v_fmac_f32 v40, s91, v119\n\t"
        "v_fmac_f32 v40, s92, v120\n\t" "v_fmac_f32 v40, s93, v121\n\t"
        "v_fmac_f32 v40, s94, v122\n\t" "v_fmac_f32 v40, s95, v123\n\t"
        "v_fmac_f32 v40, s96, v124\n\t" "v_fmac_f32 v40, s97, v125\n\t"
        "v_fmac_f32 v40, s98, v126\n\t" "v_fmac_f32 v40, s99, v127\n\t"
        // T = rn(s1+s2); d = rn(T - 2*M)  (fma with inline -2.0)
        "v_add_f32 v41, v41, %[s2k]\n\t"
        "v_fma_f32 v40, v40, -2.0, v41\n\t"
        // value-min butterfly: xor 1,2,4,8,16 via ds_swizzle, xor 32 via bpermute
        "v_mov_b32 v42, v40\n\t"
        "ds_swizzle_b32 v43, v42 offset:0x041F\n\t"
        "s_waitcnt lgkmcnt(0)\n\t"
        "v_min_f32 v42, v42, v43\n\t"
        "ds_swizzle_b32 v43, v42 offset:0x081F\n\t"
        "s_waitcnt lgkmcnt(0)\n\t"
        "v_min_f32 v42, v42, v43\n\t"
        "ds_swizzle_b32 v43, v42 offset:0x101F\n\t"
        "s_waitcnt lgkmcnt(0)\n\t"
        "v_min_f32 v42, v42, v43\n\t"
        "ds_swizzle_b32 v43, v42 offset:0x201F\n\t"
        "s_waitcnt lgkmcnt(0)\n\t"
        "v_min_f32 v42, v42, v43\n\t"
        "ds_swizzle_b32 v43, v42 offset:0x401F\n\t"
        "s_waitcnt lgkmcnt(0)\n\t"
        "v_min_f32 v42, v42, v43\n\t"
        "ds_bpermute_b32 v43, %[x32], v42\n\t"
        "s_waitcnt lgkmcnt(0)\n\t"
        "v_min_f32 v42, v42, v43\n\t"
        // lowest lane among equals -> lowest k (exact tie-break)
        "v_cmp_eq_f32 vcc, v40, v42\n\t"
        "s_ff1_i32_b64 s33, vcc\n\t"
        "v_add_u32 v44, s33, %[wb]\n\t"
        // one-lane write of (dmin, k) to cdl/ckl
        "s_mov_b64 s[28:29], exec\n\t"
        "s_mov_b64 exec, 1\n\t"
        "ds_write_b32 %[cda], v42\n\t"
        "ds_write_b32 %[cka], v44\n\t"
        "s_mov_b64 exec, s[28:29]\n\t"
        // advance + loop
        "v_add_u32 %[s1a], 4, %[s1a]\n\t"
        "v_add_u32 %[cda], 4, %[cda]\n\t"
        "v_add_u32 %[cka], 4, %[cka]\n\t"
        "s_add_u32 s34, s34, 0x100\n\t"
        "s_addc_u32 s35, s35, 0\n\t"
        "s_sub_i32 s26, s26, 1\n\t"
        "s_cmp_lg_u32 s26, 0\n\t"
        "s_cbranch_scc1 1b\n\t"
        : [s1a] "+v"(s1a), [cda] "+v"(cda), [cka] "+v"(cka)
        : [cbr] "v"(cbrow), [zrow] "s"(zrow), [s2k] "v"(s2k),
          [wb] "v"(wbase), [x32] "v"(x32a)
        : "memory", "vcc", "s26", "s28", "s29", "s33", "s34", "s35",
          "s36","s37","s38","s39","s40","s41","s42","s43","s44","s45",
          "s46","s47","s48","s49","s50","s51","s52","s53","s54","s55",
          "s56","s57","s58","s59","s60","s61","s62","s63","s64","s65",
          "s66","s67","s68","s69","s70","s71","s72","s73","s74","s75",
          "s76","s77","s78","s79","s80","s81","s82","s83","s84","s85",
          "s86","s87","s88","s89","s90","s91","s92","s93","s94","s95",
          "s96","s97","s98","s99",
          "v40","v41","v42","v43","v44",
          "v64","v65","v66","v67","v68","v69","v70","v71",
          "v72","v73","v74","v75","v76","v77","v78","v79",
          "v80","v81","v82","v83","v84","v85","v86","v87",
          "v88","v89","v90","v91","v92","v93","v94","v95",
          "v96","v97","v98","v99","v100","v101","v102","v103",
          "v104","v105","v106","v107","v108","v109","v110","v111",
          "v112","v113","v114","v115","v116","v117","v118","v119",
          "v120","v121","v122","v123","v124","v125","v126","v127");

    __syncthreads();                           // cdl/ckl complete, zt reads done

    // ---- cross-wave merge: ascending w, strict < => lowest k on ties ----
    if (tid < 128) {
        float bd = cdl[0][tid]; int bk = ckl[0][tid];
        #pragma unroll
        for (int ww = 1; ww < 8; ++ww) {
            const float dw = cdl[ww][tid];
            const int   kw = ckl[ww][tid];
            if (dw < bd) { bd = dw; bk = kw; }
        }
        ifin[tid] = bk;
        ow[8388608 + n0 + tid] = (float)bk;    // overwrite s1 slice (safe now)
    }
    __syncthreads();

    // ---- z_q gather: 128 samples x 64 floats, coalesced 16B stores ----
    float* ob = ow + ((size_t)n0 << 6);        // overwrite z_t slice (safe now)
    #pragma unroll
    for (int it = 0; it < 4; ++it) {
        const int o    = it * 2048 + (tid << 2);
        const int sloc = o >> 6;
        const int c0   = o & 63;
        const int idx  = ifin[sloc] & 511;
        const fl4 v = *(const fl4*)(cb + ((size_t)idx << 6) + c0);
        *(fl4*)(ob + o) = v;
    }
}

extern "C" void kernel_launch(void* const* d_in, const int* in_sizes, int n_in,
                              void* d_out, int out_size, void* d_ws, size_t ws_size,
                              hipStream_t stream) {
    const float* z  = (const float*)d_in[0];   // z_e fp32 [32,64,64,64]
    const float* cb = (const float*)d_in[1];   // codebook fp32 [512,64]
    float* out = (float*)d_out;                // fp32: z_q [8388608] ++ idx [131072]
    vq16a<<<512, 256, 0, stream>>>(z, out);
    vq16b<<<1024, 512, 0, stream>>>(cb, out, out + 8388608, out);
}

// Round 8
// 259.046 us; speedup vs baseline: 1.5828x; 1.5828x over previous
//
#include <hip/hip_runtime.h>

// VQ-VAE quantizer — round 17: R16's exact asm loop + latency/occupancy fixes.
// Inputs fp32: z_e [32,64,64,64], codebook [512,64].
// Output fp32: z_q [8388608] ++ indices-as-float [131072].
//
// Reference (np, fp32): d = rn( rn(s1 + s2[k]) - 2*M32[k] ), argmin ties->lowest.
//   M32 chain: c-ascending single-accumulator fma — v_fmac_f32 IS rn(S0*S1+D).
//   d: v_fma_f32 d, M, -2.0, T == rn(T - 2*M). argmin: exact min butterfly +
//   v_cmp_eq + s_ff1 -> lowest lane = lowest k; cross-wave merge ascending w,
//   strict <. All bit-identical to R13/R16 (both passed, absmax 0).
//
// R16 post-mortem: known-exact instruction stream still ran 2.1x the issue
// model => the "extra VALU op per fma" theory is dead. Real cause: occupancy
// fell to 23% (8 waves/CU) while each sample has ~1100 cyc of SERIAL latency
// (s_load wait ~200, 6 LDS butterfly round trips ~720, fmac chain 256) ->
// latency-bound. R17 keeps the stream, fixes the two latency killers:
//   1. __launch_bounds__(512,4) (R13/R15 had a min-waves decl and held 51%;
//      R16 dropped it and halved) + lean clobber set v20..v127, no compiler
//      arrays => no hidden AGPR growth.
//   2. 2 samples/iter: butterflies interleaved (LDS latencies overlap),
//      s1 as one ds_read_b64, loop overhead halved.

typedef __attribute__((ext_vector_type(4))) float fl4;

// ---------- kernel A: z -> z_t[n][64] (row-contiguous) + s1[n] ----------
// (verbatim R13a — proven; ~17us implied from bench deltas)
__global__ __launch_bounds__(256)
void vq17a(const float* __restrict__ z, float* __restrict__ ow)
{
    __shared__ float zl[256][65];              // +1 dword pad: conflict-free
    const int tid = threadIdx.x;
    const int n0  = blockIdx.x << 8;           // 512 blocks x 256 samples
    const int n   = n0 + tid;
    const size_t base = (size_t)(n >> 12) * 262144 + (size_t)(n & 4095);

    float p[8];
    #pragma unroll
    for (int c = 0; c < 64; ++c) {
        const float v = z[base + (size_t)c * 4096];   // coalesced across tid
        zl[tid][c] = v;
        const float sq = __fmul_rn(v, v);             // np: z**2 rounds first
        if (c < 8) p[c] = sq;
        else       p[c & 7] = __fadd_rn(p[c & 7], sq);
    }
    const float s1 = __fadd_rn(__fadd_rn(__fadd_rn(p[0],p[1]),__fadd_rn(p[2],p[3])),
                               __fadd_rn(__fadd_rn(p[4],p[5]),__fadd_rn(p[6],p[7])));
    ow[8388608 + n] = s1;                             // s1 -> indices region
    __syncthreads();

    float* zt = ow + (size_t)n0 * 64;
    #pragma unroll
    for (int j = 0; j < 16; ++j) {
        const int f  = j * 256 + tid;
        const int nl = f >> 4, c0 = (f & 15) << 2;
        fl4 v;
        #pragma unroll
        for (int e = 0; e < 4; ++e) v[e] = zl[nl][c0 + e];
        *(fl4*)(zt + ((size_t)f << 2)) = v;
    }
}

// fmac line generators: z[c] = s(36+c), cb[c] = v(64+c)
#define F0(S,V) "v_fmac_f32 v24, s" #S ", v" #V "\n\t"
#define F1(S,V) "v_fmac_f32 v25, s" #S ", v" #V "\n\t"

// ---------- kernel B: lane=code, one asm block, 2 samples/iter ----------
__global__ __launch_bounds__(512, 4)
void vq17b(const float* __restrict__ cb,
           const float* __restrict__ zt,      // == ow (z_q region)
           const float* __restrict__ s1g,     // == ow + 8388608
           float* __restrict__ ow)
{
    __shared__ __align__(16) float s1l[128];
    __shared__ __align__(16) float cdl[8][128];   // per-wave candidate d
    __shared__ __align__(16) int   ckl[8][128];   // per-wave candidate k
    __shared__ int   ifin[128];

    const int tid  = threadIdx.x;
    const int w    = tid >> 6;                // wave 0..7
    const int lane = tid & 63;
    const int n0   = blockIdx.x << 7;         // 1024 blocks x 128 samples
    const int k    = (w << 6) + lane;         // this lane's code

    // s2 for this code (np order) — short-lived C++, dies before the asm
    float s2k;
    {
        const float* row = cb + ((size_t)k << 6);
        float q[8];
        #pragma unroll
        for (int j = 0; j < 8; ++j) q[j] = __fmul_rn(row[j], row[j]);
        #pragma unroll
        for (int m = 1; m < 8; ++m)
            #pragma unroll
            for (int j = 0; j < 8; ++j)
                q[j] = __fadd_rn(q[j], __fmul_rn(row[m*8+j], row[m*8+j]));
        s2k = __fadd_rn(__fadd_rn(__fadd_rn(q[0],q[1]),__fadd_rn(q[2],q[3])),
                        __fadd_rn(__fadd_rn(q[4],q[5]),__fadd_rn(q[6],q[7])));
    }

    if (tid < 128) s1l[tid] = s1g[n0 + tid];  // read BEFORE overwrite
    __syncthreads();

    const float* cbrow = cb + ((size_t)k << 6);   // lane-varying, 16B aligned
    const float* zrow  = zt + ((size_t)n0 << 6);  // uniform -> SGPR pair
    unsigned s1a = (unsigned)(unsigned long long)&s1l[0];
    unsigned cda = (unsigned)(unsigned long long)&cdl[w][0];
    unsigned cka = (unsigned)(unsigned long long)&ckl[w][0];
    const int x32a  = (lane ^ 32) << 2;           // bpermute addr
    const int wbase = w << 6;

    asm volatile(
        // ---- codebook row -> v[64:127], once ----
        "global_load_dwordx4 v[64:67],   %[cbr], off\n\t"
        "global_load_dwordx4 v[68:71],   %[cbr], off offset:16\n\t"
        "global_load_dwordx4 v[72:75],   %[cbr], off offset:32\n\t"
        "global_load_dwordx4 v[76:79],   %[cbr], off offset:48\n\t"
        "global_load_dwordx4 v[80:83],   %[cbr], off offset:64\n\t"
        "global_load_dwordx4 v[84:87],   %[cbr], off offset:80\n\t"
        "global_load_dwordx4 v[88:91],   %[cbr], off offset:96\n\t"
        "global_load_dwordx4 v[92:95],   %[cbr], off offset:112\n\t"
        "global_load_dwordx4 v[96:99],   %[cbr], off offset:128\n\t"
        "global_load_dwordx4 v[100:103], %[cbr], off offset:144\n\t"
        "global_load_dwordx4 v[104:107], %[cbr], off offset:160\n\t"
        "global_load_dwordx4 v[108:111], %[cbr], off offset:176\n\t"
        "global_load_dwordx4 v[112:115], %[cbr], off offset:192\n\t"
        "global_load_dwordx4 v[116:119], %[cbr], off offset:208\n\t"
        "global_load_dwordx4 v[120:123], %[cbr], off offset:224\n\t"
        "global_load_dwordx4 v[124:127], %[cbr], off offset:240\n\t"
        "s_mov_b64 s[34:35], %[zr]\n\t"
        "s_movk_i32 s33, 64\n\t"
        "s_waitcnt vmcnt(0)\n\t"
        // ---- 64 iterations x 2 samples ----
        "1:\n\t"
        "ds_read_b64 v[20:21], %[s1a]\n\t"            // s1 pair (s0,s1)
        "s_load_dwordx16 s[36:51], s[34:35], 0x0\n\t"
        "s_load_dwordx16 s[52:67], s[34:35], 0x40\n\t"
        "s_load_dwordx16 s[68:83], s[34:35], 0x80\n\t"
        "s_load_dwordx16 s[84:99], s[34:35], 0xC0\n\t"
        "v_mov_b32 v24, 0\n\t"
        "s_waitcnt lgkmcnt(0)\n\t"
        // sample 0: 64-step c-ascending single-accumulator chain (exact grid)
        F0(36,64)  F0(37,65)  F0(38,66)  F0(39,67)  F0(40,68)  F0(41,69)  F0(42,70)  F0(43,71)
        F0(44,72)  F0(45,73)  F0(46,74)  F0(47,75)  F0(48,76)  F0(49,77)  F0(50,78)  F0(51,79)
        F0(52,80)  F0(53,81)  F0(54,82)  F0(55,83)  F0(56,84)  F0(57,85)  F0(58,86)  F0(59,87)
        F0(60,88)  F0(61,89)  F0(62,90)  F0(63,91)  F0(64,92)  F0(65,93)  F0(66,94)  F0(67,95)
        F0(68,96)  F0(69,97)  F0(70,98)  F0(71,99)  F0(72,100) F0(73,101) F0(74,102) F0(75,103)
        F0(76,104) F0(77,105) F0(78,106) F0(79,107) F0(80,108) F0(81,109) F0(82,110) F0(83,111)
        F0(84,112) F0(85,113) F0(86,114) F0(87,115) F0(88,116) F0(89,117) F0(90,118) F0(91,119)
        F0(92,120) F0(93,121) F0(94,122) F0(95,123) F0(96,124) F0(97,125) F0(98,126) F0(99,127)
        "v_add_f32 v20, %[s2k], v20\n\t"              // T0 = rn(s1+s2)
        "v_fma_f32 v28, v24, -2.0, v20\n\t"           // d0 = rn(T0 - 2*M0)
        // sample 1
        "s_add_u32 s34, s34, 0x100\n\t"
        "s_addc_u32 s35, s35, 0\n\t"
        "s_load_dwordx16 s[36:51], s[34:35], 0x0\n\t"
        "s_load_dwordx16 s[52:67], s[34:35], 0x40\n\t"
        "s_load_dwordx16 s[68:83], s[34:35], 0x80\n\t"
        "s_load_dwordx16 s[84:99], s[34:35], 0xC0\n\t"
        "v_mov_b32 v25, 0\n\t"
        "s_waitcnt lgkmcnt(0)\n\t"
        F1(36,64)  F1(37,65)  F1(38,66)  F1(39,67)  F1(40,68)  F1(41,69)  F1(42,70)  F1(43,71)
        F1(44,72)  F1(45,73)  F1(46,74)  F1(47,75)  F1(48,76)  F1(49,77)  F1(50,78)  F1(51,79)
        F1(52,80)  F1(53,81)  F1(54,82)  F1(55,83)  F1(56,84)  F1(57,85)  F1(58,86)  F1(59,87)
        F1(60,88)  F1(61,89)  F1(62,90)  F1(63,91)  F1(64,92)  F1(65,93)  F1(66,94)  F1(67,95)
        F1(68,96)  F1(69,97)  F1(70,98)  F1(71,99)  F1(72,100) F1(73,101) F1(74,102) F1(75,103)
        F1(76,104) F1(77,105) F1(78,106) F1(79,107) F1(80,108) F1(81,109) F1(82,110) F1(83,111)
        F1(84,112) F1(85,113) F1(86,114) F1(87,115) F1(88,116) F1(89,117) F1(90,118) F1(91,119)
        F1(92,120) F1(93,121) F1(94,122) F1(95,123) F1(96,124) F1(97,125) F1(98,126) F1(99,127)
        "v_add_f32 v21, %[s2k], v21\n\t"              // T1
        "v_fma_f32 v29, v25, -2.0, v21\n\t"           // d1
        "s_add_u32 s34, s34, 0x100\n\t"
        "s_addc_u32 s35, s35, 0\n\t"
        // ---- two interleaved value-min butterflies (latencies overlap) ----
        "v_mov_b32 v30, v28\n\t"
        "v_mov_b32 v31, v29\n\t"
        "ds_swizzle_b32 v40, v30 offset:0x041F\n\t"
        "ds_swizzle_b32 v41, v31 offset:0x041F\n\t"
        "s_waitcnt lgkmcnt(0)\n\t"
        "v_min_f32 v30, v30, v40\n\t"
        "v_min_f32 v31, v31, v41\n\t"
        "ds_swizzle_b32 v40, v30 offset:0x081F\n\t"
        "ds_swizzle_b32 v41, v31 offset:0x081F\n\t"
        "s_waitcnt lgkmcnt(0)\n\t"
        "v_min_f32 v30, v30, v40\n\t"
        "v_min_f32 v31, v31, v41\n\t"
        "ds_swizzle_b32 v40, v30 offset:0x101F\n\t"
        "ds_swizzle_b32 v41, v31 offset:0x101F\n\t"
        "s_waitcnt lgkmcnt(0)\n\t"
        "v_min_f32 v30, v30, v40\n\t"
        "v_min_f32 v31, v31, v41\n\t"
        "ds_swizzle_b32 v40, v30 offset:0x201F\n\t"
        "ds_swizzle_b32 v41, v31 offset:0x201F\n\t"
        "s_waitcnt lgkmcnt(0)\n\t"
        "v_min_f32 v30, v30, v40\n\t"
        "v_min_f32 v31, v31, v41\n\t"
        "ds_swizzle_b32 v40, v30 offset:0x401F\n\t"
        "ds_swizzle_b32 v41, v31 offset:0x401F\n\t"
        "s_waitcnt lgkmcnt(0)\n\t"
        "v_min_f32 v30, v30, v40\n\t"
        "v_min_f32 v31, v31, v41\n\t"
        "ds_bpermute_b32 v40, %[x32], v30\n\t"
        "ds_bpermute_b32 v41, %[x32], v31\n\t"
        "s_waitcnt lgkmcnt(0)\n\t"
        "v_min_f32 v30, v30, v40\n\t"                 // dmin(s0) all lanes
        "v_min_f32 v31, v31, v41\n\t"                 // dmin(s1) all lanes
        // lowest lane among equals -> lowest k (exact tie-break)
        "v_cmp_eq_f32 vcc, v28, v30\n\t"
        "s_ff1_i32_b64 s20, vcc\n\t"
        "v_cmp_eq_f32 vcc, v29, v31\n\t"
        "s_ff1_i32_b64 s21, vcc\n\t"
        "v_add_u32 v42, s20, %[wb]\n\t"
        "v_add_u32 v43, s21, %[wb]\n\t"
        // one-lane paired writes of (dmin, k) for both samples
        "s_mov_b64 s[24:25], exec\n\t"
        "s_mov_b64 exec, 1\n\t"
        "ds_write_b64 %[cda], v[30:31]\n\t"
        "ds_write_b64 %[cka], v[42:43]\n\t"
        "s_mov_b64 exec, s[24:25]\n\t"
        // advance + loop
        "v_add_u32 %[s1a], 8, %[s1a]\n\t"
        "v_add_u32 %[cda], 8, %[cda]\n\t"
        "v_add_u32 %[cka], 8, %[cka]\n\t"
        "s_sub_i32 s33, s33, 1\n\t"
        "s_cmp_lg_u32 s33, 0\n\t"
        "s_cbranch_scc1 1b\n\t"
        : [s1a] "+v"(s1a), [cda] "+v"(cda), [cka] "+v"(cka)
        : [cbr] "v"(cbrow), [zr] "s"(zrow), [s2k] "v"(s2k),
          [wb] "v"(wbase), [x32] "v"(x32a)
        : "memory", "vcc",
          "s20","s21","s24","s25","s33","s34","s35",
          "s36","s37","s38","s39","s40","s41","s42","s43","s44","s45",
          "s46","s47","s48","s49","s50","s51","s52","s53","s54","s55",
          "s56","s57","s58","s59","s60","s61","s62","s63","s64","s65",
          "s66","s67","s68","s69","s70","s71","s72","s73","s74","s75",
          "s76","s77","s78","s79","s80","s81","s82","s83","s84","s85",
          "s86","s87","s88","s89","s90","s91","s92","s93","s94","s95",
          "s96","s97","s98","s99",
          "v20","v21","v24","v25","v28","v29","v30","v31","v40","v41","v42","v43",
          "v64","v65","v66","v67","v68","v69","v70","v71",
          "v72","v73","v74","v75","v76","v77","v78","v79",
          "v80","v81","v82","v83","v84","v85","v86","v87",
          "v88","v89","v90","v91","v92","v93","v94","v95",
          "v96","v97","v98","v99","v100","v101","v102","v103",
          "v104","v105","v106","v107","v108","v109","v110","v111",
          "v112","v113","v114","v115","v116","v117","v118","v119",
          "v120","v121","v122","v123","v124","v125","v126","v127");

    __syncthreads();                           // cdl/ckl complete, zt reads done

    // ---- cross-wave merge: ascending w, strict < => lowest k on ties ----
    if (tid < 128) {
        float bd = cdl[0][tid]; int bk = ckl[0][tid];
        #pragma unroll
        for (int ww = 1; ww < 8; ++ww) {
            const float dw = cdl[ww][tid];
            const int   kw = ckl[ww][tid];
            if (dw < bd) { bd = dw; bk = kw; }
        }
        ifin[tid] = bk;
        ow[8388608 + n0 + tid] = (float)bk;    // overwrite s1 slice (safe now)
    }
    __syncthreads();

    // ---- z_q gather: 128 samples x 64 floats, coalesced 16B stores ----
    float* ob = ow + ((size_t)n0 << 6);        // overwrite z_t slice (safe now)
    #pragma unroll
    for (int it = 0; it < 4; ++it) {
        const int o    = it * 2048 + (tid << 2);
        const int sloc = o >> 6;
        const int c0   = o & 63;
        const int idx  = ifin[sloc] & 511;
        const fl4 v = *(const fl4*)(cb + ((size_t)idx << 6) + c0);
        *(fl4*)(ob + o) = v;
    }
}

extern "C" void kernel_launch(void* const* d_in, const int* in_sizes, int n_in,
                              void* d_out, int out_size, void* d_ws, size_t ws_size,
                              hipStream_t stream) {
    const float* z  = (const float*)d_in[0];   // z_e fp32 [32,64,64,64]
    const float* cb = (const float*)d_in[1];   // codebook fp32 [512,64]
    float* out = (float*)d_out;                // fp32: z_q [8388608] ++ idx [131072]
    vq17a<<<512, 256, 0, stream>>>(z, out);
    vq17b<<<1024, 512, 0, stream>>>(cb, out, out + 8388608, out);
}

// Round 10
// 251.386 us; speedup vs baseline: 1.6310x; 1.0305x over previous
//
#include <hip/hip_runtime.h>

// VQ-VAE quantizer — round 19: R18's fast loop, made sound — ONE asm block,
// full 32KB z tile staged in C++ BEFORE it (no C++ between cb-load and use).
// Inputs fp32: z_e [32,64,64,64], codebook [512,64].
// Output fp32: z_q [8388608] ++ indices-as-float [131072].
//
// Reference (np, fp32): d = rn( rn(s1 + s2[k]) - 2*M32[k] ), argmin ties->lowest.
//   M32 chain: c-ascending single-accumulator fma (v_fmac_f32 = rn(S0*S1+D)).
//   d: v_fma_f32 d, M, -2.0, T = rn(T-2M). argmin: exact value-min reduce
//   (DPP xor1..8 + swizzle xor16 + bpermute xor32) + v_cmp_eq + s_ff1 ->
//   lowest equal lane = lowest k; cross-wave merge ascending w, strict <.
//   Reduce-tail/cmp identical to R13/R16/R17 (passed). A min reduce can only
//   break tie-selection via NaN values, never via permutation (own-lane d
//   always participates) — and d is NaN-free when cb/z regs are intact.
//
// R18 post-mortem: Output1 absmax 512 = index -1 = "no lane equal" = all-lane
// NaN d. Cause: cb-load asm and loop asm were SEPARATE blocks with C++ z-tile
// staging between them; the compiler legally used v64..127 (clobbered-by-asm
// regs are free for temps BETWEEN asms) -> codebook registers corrupted ->
// inf-inf NaN. Fix: one asm block owns cb regs from load to last use; all
// staging (32KB z tile + s1) happens in C++ BEFORE it, syncthreads, then asm.
// LDS: 32KB zl + 0.5 s1l + 4 cdl + 4 ckl + 0.5 ifin ~= 41KB -> 2-3 blocks/CU.

typedef __attribute__((ext_vector_type(4))) float fl4;

// ---------- kernel A: z -> z_t[n][64] (row-contiguous) + s1[n] ----------
// (verbatim R13a — proven across R13/R15/R16/R17, absmax 0)
__global__ __launch_bounds__(256)
void vq19a(const float* __restrict__ z, float* __restrict__ ow)
{
    __shared__ float zl[256][65];              // +1 dword pad: conflict-free
    const int tid = threadIdx.x;
    const int n0  = blockIdx.x << 8;           // 512 blocks x 256 samples
    const int n   = n0 + tid;
    const size_t base = (size_t)(n >> 12) * 262144 + (size_t)(n & 4095);

    float p[8];
    #pragma unroll
    for (int c = 0; c < 64; ++c) {
        const float v = z[base + (size_t)c * 4096];   // coalesced across tid
        zl[tid][c] = v;
        const float sq = __fmul_rn(v, v);             // np: z**2 rounds first
        if (c < 8) p[c] = sq;
        else       p[c & 7] = __fadd_rn(p[c & 7], sq);
    }
    const float s1 = __fadd_rn(__fadd_rn(__fadd_rn(p[0],p[1]),__fadd_rn(p[2],p[3])),
                               __fadd_rn(__fadd_rn(p[4],p[5]),__fadd_rn(p[6],p[7])));
    ow[8388608 + n] = s1;                             // s1 -> indices region
    __syncthreads();

    float* zt = ow + (size_t)n0 * 64;
    #pragma unroll
    for (int j = 0; j < 16; ++j) {
        const int f  = j * 256 + tid;
        const int nl = f >> 4, c0 = (f & 15) << 2;
        fl4 v;
        #pragma unroll
        for (int e = 0; e < 4; ++e) v[e] = zl[nl][c0 + e];
        *(fl4*)(zt + ((size_t)f << 2)) = v;
    }
}

// ---- asm text macros (register map: cb v64..127, bufA v20..35, bufB v36..51,
//      acc v52/53, s1 v54/55, d v56/57, red v58/59, k v60/61, tmp v62/63) ----
#define FM2(ZA,ZB,C) \
    "v_fmac_f32 v52, v" #ZA ", v" #C "\n\t" \
    "v_fmac_f32 v53, v" #ZB ", v" #C "\n\t"
#define LA4(O0,O1,O2,O3) \
    "ds_read_b128 v[20:23], %[zb] offset:" #O0 "\n\t" \
    "ds_read_b128 v[24:27], %[zb] offset:" #O1 "\n\t" \
    "ds_read_b128 v[28:31], %[zb] offset:" #O2 "\n\t" \
    "ds_read_b128 v[32:35], %[zb] offset:" #O3 "\n\t"
#define LB4(O0,O1,O2,O3) \
    "ds_read_b128 v[36:39], %[zb] offset:" #O0 "\n\t" \
    "ds_read_b128 v[40:43], %[zb] offset:" #O1 "\n\t" \
    "ds_read_b128 v[44:47], %[zb] offset:" #O2 "\n\t" \
    "ds_read_b128 v[48:51], %[zb] offset:" #O3 "\n\t"
#define FMA_A(C0,C1,C2,C3,C4,C5,C6,C7) \
    FM2(20,28,C0) FM2(21,29,C1) FM2(22,30,C2) FM2(23,31,C3) \
    FM2(24,32,C4) FM2(25,33,C5) FM2(26,34,C6) FM2(27,35,C7)
#define FMA_B(C0,C1,C2,C3,C4,C5,C6,C7) \
    FM2(36,44,C0) FM2(37,45,C1) FM2(38,46,C2) FM2(39,47,C3) \
    FM2(40,48,C4) FM2(41,49,C5) FM2(42,50,C6) FM2(43,51,C7)
#define DPPMIN(MOD) \
    "v_min_f32 v58, v58, v58 " MOD " row_mask:0xf bank_mask:0xf\n\t" \
    "v_min_f32 v59, v59, v59 " MOD " row_mask:0xf bank_mask:0xf\n\t" \
    "s_nop 1\n\t"

// ---------- kernel B: lane=code, staged tile, one asm block ----------
__global__ __launch_bounds__(512, 4)
void vq19b(const float* __restrict__ cb,
           const float* __restrict__ zt,      // == ow (z_q region)
           const float* __restrict__ s1g,     // == ow + 8388608
           float* __restrict__ ow)
{
    __shared__ __align__(16) float zl[8192];      // 32KB: 128 samples x 64 floats
    __shared__ __align__(16) float s1l[128];
    __shared__ __align__(16) float cdl[8][128];   // per-wave candidate d
    __shared__ __align__(16) int   ckl[8][128];   // per-wave candidate k
    __shared__ int   ifin[128];

    const int tid  = threadIdx.x;
    const int w    = tid >> 6;                // wave 0..7
    const int lane = tid & 63;
    const int n0   = blockIdx.x << 7;         // 1024 blocks x 128 samples
    const int k    = (w << 6) + lane;         // this lane's code

    // s2 for this code (np order) — short-lived C++, dies before the asm
    float s2k;
    {
        const float* row = cb + ((size_t)k << 6);
        float q[8];
        #pragma unroll
        for (int j = 0; j < 8; ++j) q[j] = __fmul_rn(row[j], row[j]);
        #pragma unroll
        for (int m = 1; m < 8; ++m)
            #pragma unroll
            for (int j = 0; j < 8; ++j)
                q[j] = __fadd_rn(q[j], __fmul_rn(row[m*8+j], row[m*8+j]));
        s2k = __fadd_rn(__fadd_rn(__fadd_rn(q[0],q[1]),__fadd_rn(q[2],q[3])),
                        __fadd_rn(__fadd_rn(q[4],q[5]),__fadd_rn(q[6],q[7])));
    }

    // ---- stage s1 (512B) and the FULL z tile (32KB) in C++, then barrier ----
    if (tid < 128) s1l[tid] = s1g[n0 + tid];
    {
        const fl4* src = (const fl4*)(zt + ((size_t)n0 << 6));   // 2048 fl4
        fl4* dst = (fl4*)zl;
        dst[tid]        = src[tid];
        dst[512  + tid] = src[512  + tid];
        dst[1024 + tid] = src[1024 + tid];
        dst[1536 + tid] = src[1536 + tid];
    }
    __syncthreads();   // drains the staging stores; zl/s1l visible to all

    const float* cbrow = cb + ((size_t)k << 6);   // lane-varying, 16B aligned
    unsigned s1a = (unsigned)(unsigned long long)&s1l[0];
    unsigned cda = (unsigned)(unsigned long long)&cdl[w][0];
    unsigned cka = (unsigned)(unsigned long long)&ckl[w][0];
    unsigned zb  = (unsigned)(unsigned long long)&zl[0];
    const int x32a  = (lane ^ 32) << 2;           // bpermute addr
    const int wbase = w << 6;

    // ONE asm block: cb load + 64 iterations (2 samples each). No C++ between
    // the cb registers' definition and their last use.
    asm volatile(
        "global_load_dwordx4 v[64:67],   %[cbr], off\n\t"
        "global_load_dwordx4 v[68:71],   %[cbr], off offset:16\n\t"
        "global_load_dwordx4 v[72:75],   %[cbr], off offset:32\n\t"
        "global_load_dwordx4 v[76:79],   %[cbr], off offset:48\n\t"
        "global_load_dwordx4 v[80:83],   %[cbr], off offset:64\n\t"
        "global_load_dwordx4 v[84:87],   %[cbr], off offset:80\n\t"
        "global_load_dwordx4 v[88:91],   %[cbr], off offset:96\n\t"
        "global_load_dwordx4 v[92:95],   %[cbr], off offset:112\n\t"
        "global_load_dwordx4 v[96:99],   %[cbr], off offset:128\n\t"
        "global_load_dwordx4 v[100:103], %[cbr], off offset:144\n\t"
        "global_load_dwordx4 v[104:107], %[cbr], off offset:160\n\t"
        "global_load_dwordx4 v[108:111], %[cbr], off offset:176\n\t"
        "global_load_dwordx4 v[112:115], %[cbr], off offset:192\n\t"
        "global_load_dwordx4 v[116:119], %[cbr], off offset:208\n\t"
        "global_load_dwordx4 v[120:123], %[cbr], off offset:224\n\t"
        "global_load_dwordx4 v[124:127], %[cbr], off offset:240\n\t"
        "s_movk_i32 s33, 64\n\t"
        "s_waitcnt vmcnt(0)\n\t"
        // ---- 64 iterations x 2 samples ----
        "1:\n\t"
        "v_mov_b32 v52, 0\n\t"
        "v_mov_b32 v53, 0\n\t"
        "ds_read_b64 v[54:55], %[s1a]\n\t"
        LA4(0,16,256,272)
        LB4(32,48,288,304)
        "s_waitcnt lgkmcnt(4)\n\t"
        FMA_A(64,65,66,67,68,69,70,71)
        LA4(64,80,320,336)
        "s_waitcnt lgkmcnt(4)\n\t"
        FMA_B(72,73,74,75,76,77,78,79)
        LB4(96,112,352,368)
        "s_waitcnt lgkmcnt(4)\n\t"
        FMA_A(80,81,82,83,84,85,86,87)
        LA4(128,144,384,400)
        "s_waitcnt lgkmcnt(4)\n\t"
        FMA_B(88,89,90,91,92,93,94,95)
        LB4(160,176,416,432)
        "s_waitcnt lgkmcnt(4)\n\t"
        FMA_A(96,97,98,99,100,101,102,103)
        LA4(192,208,448,464)
        "s_waitcnt lgkmcnt(4)\n\t"
        FMA_B(104,105,106,107,108,109,110,111)
        LB4(224,240,480,496)
        "s_waitcnt lgkmcnt(4)\n\t"
        FMA_A(112,113,114,115,116,117,118,119)
        "s_waitcnt lgkmcnt(0)\n\t"
        FMA_B(120,121,122,123,124,125,126,127)
        // T = rn(s1+s2); d = rn(T - 2*M)
        "v_add_f32 v54, %[s2k], v54\n\t"
        "v_add_f32 v55, %[s2k], v55\n\t"
        "v_fma_f32 v56, v52, -2.0, v54\n\t"
        "v_fma_f32 v57, v53, -2.0, v55\n\t"
        // value-min reduce: DPP xor1/2/4/8 (VALU), swizzle xor16, bpermute xor32
        "v_mov_b32 v58, v56\n\t"
        "v_mov_b32 v59, v57\n\t"
        "s_nop 1\n\t"
        DPPMIN("quad_perm:[1,0,3,2]")
        DPPMIN("quad_perm:[2,3,0,1]")
        DPPMIN("row_half_mirror")
        DPPMIN("row_mirror")
        "ds_swizzle_b32 v62, v58 offset:0x401F\n\t"
        "ds_swizzle_b32 v63, v59 offset:0x401F\n\t"
        "s_waitcnt lgkmcnt(0)\n\t"
        "v_min_f32 v58, v58, v62\n\t"
        "v_min_f32 v59, v59, v63\n\t"
        "ds_bpermute_b32 v62, %[x32], v58\n\t"
        "ds_bpermute_b32 v63, %[x32], v59\n\t"
        "s_waitcnt lgkmcnt(0)\n\t"
        "v_min_f32 v58, v58, v62\n\t"                 // dmin(s0) all lanes
        "v_min_f32 v59, v59, v63\n\t"                 // dmin(s1) all lanes
        // lowest equal lane -> lowest k (exact tie-break)
        "v_cmp_eq_f32 vcc, v56, v58\n\t"
        "s_ff1_i32_b64 s20, vcc\n\t"
        "v_cmp_eq_f32 vcc, v57, v59\n\t"
        "s_ff1_i32_b64 s21, vcc\n\t"
        "v_add_u32 v60, s20, %[wb]\n\t"
        "v_add_u32 v61, s21, %[wb]\n\t"
        // one-lane paired writes of (dmin, k)
        "s_mov_b64 s[24:25], exec\n\t"
        "s_mov_b64 exec, 1\n\t"
        "ds_write_b64 %[cda], v[58:59]\n\t"
        "ds_write_b64 %[cka], v[60:61]\n\t"
        "s_mov_b64 exec, s[24:25]\n\t"
        // advance + loop
        "v_add_u32 %[s1a], 8, %[s1a]\n\t"
        "v_add_u32 %[cda], 8, %[cda]\n\t"
        "v_add_u32 %[cka], 8, %[cka]\n\t"
        "v_add_u32 %[zb], 0x200, %[zb]\n\t"
        "s_sub_i32 s33, s33, 1\n\t"
        "s_cmp_lg_u32 s33, 0\n\t"
        "s_cbranch_scc1 1b\n\t"
        : [s1a] "+v"(s1a), [cda] "+v"(cda), [cka] "+v"(cka), [zb] "+v"(zb)
        : [cbr] "v"(cbrow), [s2k] "v"(s2k), [wb] "v"(wbase), [x32] "v"(x32a)
        : "memory", "vcc", "s20","s21","s24","s25","s33",
          "v20","v21","v22","v23","v24","v25","v26","v27",
          "v28","v29","v30","v31","v32","v33","v34","v35",
          "v36","v37","v38","v39","v40","v41","v42","v43",
          "v44","v45","v46","v47","v48","v49","v50","v51",
          "v52","v53","v54","v55","v56","v57","v58","v59",
          "v60","v61","v62","v63",
          "v64","v65","v66","v67","v68","v69","v70","v71",
          "v72","v73","v74","v75","v76","v77","v78","v79",
          "v80","v81","v82","v83","v84","v85","v86","v87",
          "v88","v89","v90","v91","v92","v93","v94","v95",
          "v96","v97","v98","v99","v100","v101","v102","v103",
          "v104","v105","v106","v107","v108","v109","v110","v111",
          "v112","v113","v114","v115","v116","v117","v118","v119",
          "v120","v121","v122","v123","v124","v125","v126","v127");

    __syncthreads();                          // cdl/ckl complete, zl reads done

    // ---- cross-wave merge: ascending w, strict < => lowest k on ties ----
    if (tid < 128) {
        float bd = cdl[0][tid]; int bk = ckl[0][tid];
        #pragma unroll
        for (int ww = 1; ww < 8; ++ww) {
            const float dw = cdl[ww][tid];
            const int   kw = ckl[ww][tid];
            if (dw < bd) { bd = dw; bk = kw; }
        }
        ifin[tid] = bk;
        ow[8388608 + n0 + tid] = (float)bk;   // overwrite s1 slice (safe now)
    }
    __syncthreads();

    // ---- z_q gather: 128 samples x 64 floats, coalesced 16B stores ----
    float* ob = ow + ((size_t)n0 << 6);       // overwrite z_t slice (safe now)
    #pragma unroll
    for (int it = 0; it < 4; ++it) {
        const int o    = it * 2048 + (tid << 2);
        const int sloc = o >> 6;
        const int c0   = o & 63;
        const int idx  = ifin[sloc] & 511;
        const fl4 v = *(const fl4*)(cb + ((size_t)idx << 6) + c0);
        *(fl4*)(ob + o) = v;
    }
}

extern "C" void kernel_launch(void* const* d_in, const int* in_sizes, int n_in,
                              void* d_out, int out_size, void* d_ws, size_t ws_size,
                              hipStream_t stream) {
    const float* z  = (const float*)d_in[0];   // z_e fp32 [32,64,64,64]
    const float* cb = (const float*)d_in[1];   // codebook fp32 [512,64]
    float* out = (float*)d_out;                // fp32: z_q [8388608] ++ idx [131072]
    vq19a<<<512, 256, 0, stream>>>(z, out);
    vq19b<<<1024, 512, 0, stream>>>(cb, out, out + 8388608, out);
}

// Round 11
// 248.169 us; speedup vs baseline: 1.6521x; 1.0130x over previous
//
#include <hip/hip_runtime.h>

// VQ-VAE quantizer — round 20: R19 + 4-sample iterations (4 fmac chains at
// dep-distance 8 cyc). Everything outside the asm loop body is verbatim R19
// (passed, absmax 0).
// Inputs fp32: z_e [32,64,64,64], codebook [512,64].
// Output fp32: z_q [8388608] ++ indices-as-float [131072].
//
// Reference (np, fp32): d = rn( rn(s1 + s2[k]) - 2*M32[k] ), argmin ties->lowest.
//   M32 chain: c-ascending single-accumulator fma (v_fmac_f32 = rn(S0*S1+D)).
//   d: v_fma_f32 d, M, -2.0, T = rn(T-2M). argmin: exact value-min reduce
//   (DPP xor1..8 + swizzle xor16 + bpermute xor32) + v_cmp_eq + s_ff1 ->
//   lowest equal lane = lowest k; cross-wave merge ascending w, strict <.
//
// R17/R19 post-mortem: removing 6 serial LDS trips + all exposed SMEM waits
// changed NOTHING (195->193us). True VALU issue duty ~35% (VALUBusy 76% is
// the gfx94x SIMD-16 formula, 2x-inflated on gfx950). The invariant across
// both: TWO interleaved 64-deep v_fmac self-accum chains at dep-distance
// 4 cyc. If fmac RMW latency is ~8 cyc (VOP3 v_fma's ~4 cyc is for distinct
// dest), 128 fmacs cost 512 cyc not 256 -> 512+reduce~260+waits ~= 905 =
// measured, in BOTH rounds. R20 tests this: 4 chains at dep-distance 8 cyc
// -> fmacs become pure issue; reduce tail amortized 4x. LDS traffic per
// sample deliberately UNCHANGED (clean A/B: no gain => LDS pipe is the wall).

typedef __attribute__((ext_vector_type(4))) float fl4;

// ---------- kernel A: z -> z_t[n][64] (row-contiguous) + s1[n] ----------
// (verbatim R13a — proven across R13/R15..R19, absmax 0)
__global__ __launch_bounds__(256)
void vq20a(const float* __restrict__ z, float* __restrict__ ow)
{
    __shared__ float zl[256][65];              // +1 dword pad: conflict-free
    const int tid = threadIdx.x;
    const int n0  = blockIdx.x << 8;           // 512 blocks x 256 samples
    const int n   = n0 + tid;
    const size_t base = (size_t)(n >> 12) * 262144 + (size_t)(n & 4095);

    float p[8];
    #pragma unroll
    for (int c = 0; c < 64; ++c) {
        const float v = z[base + (size_t)c * 4096];   // coalesced across tid
        zl[tid][c] = v;
        const float sq = __fmul_rn(v, v);             // np: z**2 rounds first
        if (c < 8) p[c] = sq;
        else       p[c & 7] = __fadd_rn(p[c & 7], sq);
    }
    const float s1 = __fadd_rn(__fadd_rn(__fadd_rn(p[0],p[1]),__fadd_rn(p[2],p[3])),
                               __fadd_rn(__fadd_rn(p[4],p[5]),__fadd_rn(p[6],p[7])));
    ow[8388608 + n] = s1;                             // s1 -> indices region
    __syncthreads();

    float* zt = ow + (size_t)n0 * 64;
    #pragma unroll
    for (int j = 0; j < 16; ++j) {
        const int f  = j * 256 + tid;
        const int nl = f >> 4, c0 = (f & 15) << 2;
        fl4 v;
        #pragma unroll
        for (int e = 0; e < 4; ++e) v[e] = zl[nl][c0 + e];
        *(fl4*)(zt + ((size_t)f << 2)) = v;
    }
}

// ---- asm text macros ----
// Register map: bufA v20..35 (4ch x 4samples: [si]=v(20+si*4+cj)), bufB v36..51,
// acc v52..55, s1/T v56..59, d v60..63, cb v64..127.
// After d is formed: red reuses v52..55, LDS tmp reuses v56..59, k reuses v20..23.
//
// FCJ: one channel (cb reg CB) fmac'd into all 4 sample accumulators.
// Each acc's chain is c-ascending single-accumulator: the exact ref grid.
#define FCJ(Z0,Z1,Z2,Z3,CB) \
    "v_fmac_f32 v52, v" #Z0 ", v" #CB "\n\t" \
    "v_fmac_f32 v53, v" #Z1 ", v" #CB "\n\t" \
    "v_fmac_f32 v54, v" #Z2 ", v" #CB "\n\t" \
    "v_fmac_f32 v55, v" #Z3 ", v" #CB "\n\t"
#define FMA_A(C0,C1,C2,C3) \
    FCJ(20,24,28,32,C0) FCJ(21,25,29,33,C1) FCJ(22,26,30,34,C2) FCJ(23,27,31,35,C3)
#define FMA_B(C0,C1,C2,C3) \
    FCJ(36,40,44,48,C0) FCJ(37,41,45,49,C1) FCJ(38,42,46,50,C2) FCJ(39,43,47,51,C3)
// LA/LB: one 4-channel chunk for 4 samples (sample si row at zb + si*256).
#define LA4(O0,O1,O2,O3) \
    "ds_read_b128 v[20:23], %[zb] offset:" #O0 "\n\t" \
    "ds_read_b128 v[24:27], %[zb] offset:" #O1 "\n\t" \
    "ds_read_b128 v[28:31], %[zb] offset:" #O2 "\n\t" \
    "ds_read_b128 v[32:35], %[zb] offset:" #O3 "\n\t"
#define LB4(O0,O1,O2,O3) \
    "ds_read_b128 v[36:39], %[zb] offset:" #O0 "\n\t" \
    "ds_read_b128 v[40:43], %[zb] offset:" #O1 "\n\t" \
    "ds_read_b128 v[44:47], %[zb] offset:" #O2 "\n\t" \
    "ds_read_b128 v[48:51], %[zb] offset:" #O3 "\n\t"
// DPP min stage applied to the 4 interleaved reduce regs (distance 4: no nops)
#define DPPMIN4(MOD) \
    "v_min_f32 v52, v52, v52 " MOD " row_mask:0xf bank_mask:0xf\n\t" \
    "v_min_f32 v53, v53, v53 " MOD " row_mask:0xf bank_mask:0xf\n\t" \
    "v_min_f32 v54, v54, v54 " MOD " row_mask:0xf bank_mask:0xf\n\t" \
    "v_min_f32 v55, v55, v55 " MOD " row_mask:0xf bank_mask:0xf\n\t"

// ---------- kernel B: lane=code, staged tile, one asm block, 4 samples/iter ----------
__global__ __launch_bounds__(512, 4)
void vq20b(const float* __restrict__ cb,
           const float* __restrict__ zt,      // == ow (z_q region)
           const float* __restrict__ s1g,     // == ow + 8388608
           float* __restrict__ ow)
{
    __shared__ __align__(16) float zl[8192];      // 32KB: 128 samples x 64 floats
    __shared__ __align__(16) float s1l[128];
    __shared__ __align__(16) float cdl[8][128];   // per-wave candidate d
    __shared__ __align__(16) int   ckl[8][128];   // per-wave candidate k
    __shared__ int   ifin[128];

    const int tid  = threadIdx.x;
    const int w    = tid >> 6;                // wave 0..7
    const int lane = tid & 63;
    const int n0   = blockIdx.x << 7;         // 1024 blocks x 128 samples
    const int k    = (w << 6) + lane;         // this lane's code

    // s2 for this code (np order) — short-lived C++, dies before the asm
    float s2k;
    {
        const float* row = cb + ((size_t)k << 6);
        float q[8];
        #pragma unroll
        for (int j = 0; j < 8; ++j) q[j] = __fmul_rn(row[j], row[j]);
        #pragma unroll
        for (int m = 1; m < 8; ++m)
            #pragma unroll
            for (int j = 0; j < 8; ++j)
                q[j] = __fadd_rn(q[j], __fmul_rn(row[m*8+j], row[m*8+j]));
        s2k = __fadd_rn(__fadd_rn(__fadd_rn(q[0],q[1]),__fadd_rn(q[2],q[3])),
                        __fadd_rn(__fadd_rn(q[4],q[5]),__fadd_rn(q[6],q[7])));
    }

    // ---- stage s1 (512B) and the FULL z tile (32KB) in C++, then barrier ----
    if (tid < 128) s1l[tid] = s1g[n0 + tid];
    {
        const fl4* src = (const fl4*)(zt + ((size_t)n0 << 6));   // 2048 fl4
        fl4* dst = (fl4*)zl;
        dst[tid]        = src[tid];
        dst[512  + tid] = src[512  + tid];
        dst[1024 + tid] = src[1024 + tid];
        dst[1536 + tid] = src[1536 + tid];
    }
    __syncthreads();   // zl/s1l visible to all

    const float* cbrow = cb + ((size_t)k << 6);   // lane-varying, 16B aligned
    unsigned s1a = (unsigned)(unsigned long long)&s1l[0];
    unsigned cda = (unsigned)(unsigned long long)&cdl[w][0];
    unsigned cka = (unsigned)(unsigned long long)&ckl[w][0];
    unsigned zb  = (unsigned)(unsigned long long)&zl[0];
    const int x32a  = (lane ^ 32) << 2;           // bpermute addr
    const int wbase = w << 6;

    // ONE asm block: cb load + 32 iterations (4 samples each). No C++ between
    // the cb registers' definition and their last use (R18 lesson).
    asm volatile(
        "global_load_dwordx4 v[64:67],   %[cbr], off\n\t"
        "global_load_dwordx4 v[68:71],   %[cbr], off offset:16\n\t"
        "global_load_dwordx4 v[72:75],   %[cbr], off offset:32\n\t"
        "global_load_dwordx4 v[76:79],   %[cbr], off offset:48\n\t"
        "global_load_dwordx4 v[80:83],   %[cbr], off offset:64\n\t"
        "global_load_dwordx4 v[84:87],   %[cbr], off offset:80\n\t"
        "global_load_dwordx4 v[88:91],   %[cbr], off offset:96\n\t"
        "global_load_dwordx4 v[92:95],   %[cbr], off offset:112\n\t"
        "global_load_dwordx4 v[96:99],   %[cbr], off offset:128\n\t"
        "global_load_dwordx4 v[100:103], %[cbr], off offset:144\n\t"
        "global_load_dwordx4 v[104:107], %[cbr], off offset:160\n\t"
        "global_load_dwordx4 v[108:111], %[cbr], off offset:176\n\t"
        "global_load_dwordx4 v[112:115], %[cbr], off offset:192\n\t"
        "global_load_dwordx4 v[116:119], %[cbr], off offset:208\n\t"
        "global_load_dwordx4 v[120:123], %[cbr], off offset:224\n\t"
        "global_load_dwordx4 v[124:127], %[cbr], off offset:240\n\t"
        "s_movk_i32 s33, 32\n\t"
        "s_waitcnt vmcnt(0)\n\t"
        // ---- 32 iterations x 4 samples ----
        "1:\n\t"
        "v_mov_b32 v52, 0\n\t"
        "v_mov_b32 v53, 0\n\t"
        "v_mov_b32 v54, 0\n\t"
        "v_mov_b32 v55, 0\n\t"
        "ds_read_b128 v[56:59], %[s1a]\n\t"           // s1 quad
        LA4(0,256,512,768)                            // chunk 0 (ch 0-3)
        LB4(16,272,528,784)                           // chunk 1 (ch 4-7)
        "s_waitcnt lgkmcnt(4)\n\t"
        FMA_A(64,65,66,67)
        LA4(32,288,544,800)                           // chunk 2
        "s_waitcnt lgkmcnt(4)\n\t"
        FMA_B(68,69,70,71)
        LB4(48,304,560,816)                           // chunk 3
        "s_waitcnt lgkmcnt(4)\n\t"
        FMA_A(72,73,74,75)
        LA4(64,320,576,832)                           // chunk 4
        "s_waitcnt lgkmcnt(4)\n\t"
        FMA_B(76,77,78,79)
        LB4(80,336,592,848)                           // chunk 5
        "s_waitcnt lgkmcnt(4)\n\t"
        FMA_A(80,81,82,83)
        LA4(96,352,608,864)                           // chunk 6
        "s_waitcnt lgkmcnt(4)\n\t"
        FMA_B(84,85,86,87)
        LB4(112,368,624,880)                          // chunk 7
        "s_waitcnt lgkmcnt(4)\n\t"
        FMA_A(88,89,90,91)
        LA4(128,384,640,896)                          // chunk 8
        "s_waitcnt lgkmcnt(4)\n\t"
        FMA_B(92,93,94,95)
        LB4(144,400,656,912)                          // chunk 9
        "s_waitcnt lgkmcnt(4)\n\t"
        FMA_A(96,97,98,99)
        LA4(160,416,672,928)                          // chunk 10
        "s_waitcnt lgkmcnt(4)\n\t"
        FMA_B(100,101,102,103)
        LB4(176,432,688,944)                          // chunk 11
        "s_waitcnt lgkmcnt(4)\n\t"
        FMA_A(104,105,106,107)
        LA4(192,448,704,960)                          // chunk 12
        "s_waitcnt lgkmcnt(4)\n\t"
        FMA_B(108,109,110,111)
        LB4(208,464,720,976)                          // chunk 13
        "s_waitcnt lgkmcnt(4)\n\t"
        FMA_A(112,113,114,115)
        LA4(224,480,736,992)                          // chunk 14
        "s_waitcnt lgkmcnt(4)\n\t"
        FMA_B(116,117,118,119)
        LB4(240,496,752,1008)                         // chunk 15
        "s_waitcnt lgkmcnt(4)\n\t"
        FMA_A(120,121,122,123)
        "s_waitcnt lgkmcnt(0)\n\t"
        FMA_B(124,125,126,127)
        // T = rn(s1+s2) in place; d = rn(T - 2*M)
        "v_add_f32 v56, %[s2k], v56\n\t"
        "v_add_f32 v57, %[s2k], v57\n\t"
        "v_add_f32 v58, %[s2k], v58\n\t"
        "v_add_f32 v59, %[s2k], v59\n\t"
        "v_fma_f32 v60, v52, -2.0, v56\n\t"
        "v_fma_f32 v61, v53, -2.0, v57\n\t"
        "v_fma_f32 v62, v54, -2.0, v58\n\t"
        "v_fma_f32 v63, v55, -2.0, v59\n\t"
        // value-min reduce: red regs v52..55 <- d; DPP xor1/2/4/8 (4-way
        // interleave: >=4 instr spacing, no hazard nops), swizzle xor16,
        // bpermute xor32 (one pair of LDS trips for all 4 samples)
        "v_mov_b32 v52, v60\n\t"
        "v_mov_b32 v53, v61\n\t"
        "v_mov_b32 v54, v62\n\t"
        "v_mov_b32 v55, v63\n\t"
        DPPMIN4("quad_perm:[1,0,3,2]")
        DPPMIN4("quad_perm:[2,3,0,1]")
        DPPMIN4("row_half_mirror")
        DPPMIN4("row_mirror")
        "ds_swizzle_b32 v56, v52 offset:0x401F\n\t"
        "ds_swizzle_b32 v57, v53 offset:0x401F\n\t"
        "ds_swizzle_b32 v58, v54 offset:0x401F\n\t"
        "ds_swizzle_b32 v59, v55 offset:0x401F\n\t"
        "s_waitcnt lgkmcnt(0)\n\t"
        "v_min_f32 v52, v52, v56\n\t"
        "v_min_f32 v53, v53, v57\n\t"
        "v_min_f32 v54, v54, v58\n\t"
        "v_min_f32 v55, v55, v59\n\t"
        "ds_bpermute_b32 v56, %[x32], v52\n\t"
        "ds_bpermute_b32 v57, %[x32], v53\n\t"
        "ds_bpermute_b32 v58, %[x32], v54\n\t"
        "ds_bpermute_b32 v59, %[x32], v55\n\t"
        "s_waitcnt lgkmcnt(0)\n\t"
        "v_min_f32 v52, v52, v56\n\t"                 // dmin all lanes
        "v_min_f32 v53, v53, v57\n\t"
        "v_min_f32 v54, v54, v58\n\t"
        "v_min_f32 v55, v55, v59\n\t"
        // lowest equal lane -> lowest k (exact tie-break)
        "v_cmp_eq_f32 vcc, v60, v52\n\t"
        "s_ff1_i32_b64 s20, vcc\n\t"
        "v_cmp_eq_f32 vcc, v61, v53\n\t"
        "s_ff1_i32_b64 s21, vcc\n\t"
        "v_cmp_eq_f32 vcc, v62, v54\n\t"
        "s_ff1_i32_b64 s22, vcc\n\t"
        "v_cmp_eq_f32 vcc, v63, v55\n\t"
        "s_ff1_i32_b64 s23, vcc\n\t"
        "v_add_u32 v20, s20, %[wb]\n\t"               // k quad (buf regs free)
        "v_add_u32 v21, s21, %[wb]\n\t"
        "v_add_u32 v22, s22, %[wb]\n\t"
        "v_add_u32 v23, s23, %[wb]\n\t"
        // one-lane b128 writes of (dmin x4, k x4)
        "s_mov_b64 s[24:25], exec\n\t"
        "s_mov_b64 exec, 1\n\t"
        "ds_write_b128 %[cda], v[52:55]\n\t"
        "ds_write_b128 %[cka], v[20:23]\n\t"
        "s_mov_b64 exec, s[24:25]\n\t"
        // advance + loop
        "v_add_u32 %[s1a], 16, %[s1a]\n\t"
        "v_add_u32 %[cda], 16, %[cda]\n\t"
        "v_add_u32 %[cka], 16, %[cka]\n\t"
        "v_add_u32 %[zb], 0x400, %[zb]\n\t"
        "s_sub_i32 s33, s33, 1\n\t"
        "s_cmp_lg_u32 s33, 0\n\t"
        "s_cbranch_scc1 1b\n\t"
        : [s1a] "+v"(s1a), [cda] "+v"(cda), [cka] "+v"(cka), [zb] "+v"(zb)
        : [cbr] "v"(cbrow), [s2k] "v"(s2k), [wb] "v"(wbase), [x32] "v"(x32a)
        : "memory", "vcc", "s20","s21","s22","s23","s24","s25","s33",
          "v20","v21","v22","v23","v24","v25","v26","v27",
          "v28","v29","v30","v31","v32","v33","v34","v35",
          "v36","v37","v38","v39","v40","v41","v42","v43",
          "v44","v45","v46","v47","v48","v49","v50","v51",
          "v52","v53","v54","v55","v56","v57","v58","v59",
          "v60","v61","v62","v63",
          "v64","v65","v66","v67","v68","v69","v70","v71",
          "v72","v73","v74","v75","v76","v77","v78","v79",
          "v80","v81","v82","v83","v84","v85","v86","v87",
          "v88","v89","v90","v91","v92","v93","v94","v95",
          "v96","v97","v98","v99","v100","v101","v102","v103",
          "v104","v105","v106","v107","v108","v109","v110","v111",
          "v112","v113","v114","v115","v116","v117","v118","v119",
          "v120","v121","v122","v123","v124","v125","v126","v127");

    __syncthreads();                          // cdl/ckl complete, zl reads done

    // ---- cross-wave merge: ascending w, strict < => lowest k on ties ----
    if (tid < 128) {
        float bd = cdl[0][tid]; int bk = ckl[0][tid];
        #pragma unroll
        for (int ww = 1; ww < 8; ++ww) {
            const float dw = cdl[ww][tid];
            const int   kw = ckl[ww][tid];
            if (dw < bd) { bd = dw; bk = kw; }
        }
        ifin[tid] = bk;
        ow[8388608 + n0 + tid] = (float)bk;   // overwrite s1 slice (safe now)
    }
    __syncthreads();

    // ---- z_q gather: 128 samples x 64 floats, coalesced 16B stores ----
    float* ob = ow + ((size_t)n0 << 6);       // overwrite z_t slice (safe now)
    #pragma unroll
    for (int it = 0; it < 4; ++it) {
        const int o    = it * 2048 + (tid << 2);
        const int sloc = o >> 6;
        const int c0   = o & 63;
        const int idx  = ifin[sloc] & 511;
        const fl4 v = *(const fl4*)(cb + ((size_t)idx << 6) + c0);
        *(fl4*)(ob + o) = v;
    }
}

extern "C" void kernel_launch(void* const* d_in, const int* in_sizes, int n_in,
                              void* d_out, int out_size, void* d_ws, size_t ws_size,
                              hipStream_t stream) {
    const float* z  = (const float*)d_in[0];   // z_e fp32 [32,64,64,64]
    const float* cb = (const float*)d_in[1];   // codebook fp32 [512,64]
    float* out = (float*)d_out;                // fp32: z_q [8388608] ++ idx [131072]
    vq20a<<<512, 256, 0, stream>>>(z, out);
    vq20b<<<1024, 512, 0, stream>>>(cb, out, out + 8388608, out);
}

// Round 14
// 225.762 us; speedup vs baseline: 1.8161x; 1.0993x over previous
//
#include <hip/hip_runtime.h>

// VQ-VAE quantizer — round 23: R22 (lane = SAMPLE) with the SGPR-constraint fix:
// half base = readfirstlane(h<<16) + cb  (the "s" constraint can't take values
// the compiler's divergence analysis calls thread-varying — R22 lesson).
// Inputs fp32: z_e [32,64,64,64], codebook [512,64].
// Output fp32: z_q [8388608] ++ indices-as-float [131072].
//
// Reference (np, fp32): d = rn( rn(s1 + s2[k]) - 2*M32[k] ), argmin ties->lowest.
//   M32 chain: c-ascending single-accumulator fma (v_fmac_f32 = rn(S0*S1+D)).
//   d: v_fma_f32 d, M, -2.0, T = rn(T-2M) (2M exact). argmin: per-lane strict
//   '<' scanning k ascending -> lowest k on ties. Cross-half merge h=0 first,
//   strict '<'. All chains bit-identical to R13-R20 (passed, absmax 0).
//
// R17/R19/R20 post-mortem: time rigid at ~190us across wildly different
// schedules. Invariant: lane=code forces every one of 8 waves to broadcast-
// read every z row from LDS -> 65536 b128/CU on the single DS pipe = wall.
// Fix is the decomposition: lane=sample. z: 64 VGPRs/lane, loaded once.
// cb: wave-uniform -> scalar pipe, 16-ch chunks double-buffered, lgkmcnt(0)
// drains one outstanding chunk. Two codes interleaved -> fmac dep-distance
// 4cyc = chain latency (m07). Argmin per-lane (cmp + 2 cndmask + add) — the
// butterfly machinery deleted. 8 waves = 4 sample-groups x 2 code-halves.

typedef __attribute__((ext_vector_type(4))) float fl4;

// ---------- kernel A: z -> z_t[n][64] (row-contiguous) + s1[n] ----------
// (verbatim R13a — proven across R13/R15..R20, absmax 0)
__global__ __launch_bounds__(256)
void vq23a(const float* __restrict__ z, float* __restrict__ ow)
{
    __shared__ float zl[256][65];              // +1 dword pad: conflict-free
    const int tid = threadIdx.x;
    const int n0  = blockIdx.x << 8;           // 512 blocks x 256 samples
    const int n   = n0 + tid;
    const size_t base = (size_t)(n >> 12) * 262144 + (size_t)(n & 4095);

    float p[8];
    #pragma unroll
    for (int c = 0; c < 64; ++c) {
        const float v = z[base + (size_t)c * 4096];   // coalesced across tid
        zl[tid][c] = v;
        const float sq = __fmul_rn(v, v);             // np: z**2 rounds first
        if (c < 8) p[c] = sq;
        else       p[c & 7] = __fadd_rn(p[c & 7], sq);
    }
    const float s1 = __fadd_rn(__fadd_rn(__fadd_rn(p[0],p[1]),__fadd_rn(p[2],p[3])),
                               __fadd_rn(__fadd_rn(p[4],p[5]),__fadd_rn(p[6],p[7])));
    ow[8388608 + n] = s1;                             // s1 -> indices region
    __syncthreads();

    float* zt = ow + (size_t)n0 * 64;
    #pragma unroll
    for (int j = 0; j < 16; ++j) {
        const int f  = j * 256 + tid;
        const int nl = f >> 4, c0 = (f & 15) << 2;
        fl4 v;
        #pragma unroll
        for (int e = 0; e < 4; ++e) v[e] = zl[nl][c0 + e];
        *(fl4*)(zt + ((size_t)f << 2)) = v;
    }
}

// ---- asm text macros ----
// Register map: z row v40..v103 (channel c -> v(40+c)); acc0 v32 (code k0),
// acc1 v33 (k1); s2 pair v22/23; best v24; bi v25; d0 v26; d1 v27; k-idx v28;
// s2addr v30. cb SGPR bufs: buf0 = s[36:51](k0)+s[52:67](k1), buf1 = s[68:83]
// +s[84:99]. F2: one channel for both codes — each acc's chain stays
// c-ascending single-accumulator (dep-distance 2 instrs = 4 cyc).
#define F2(SA,SB,VZ) \
    "v_fmac_f32 v32, s" #SA ", v" #VZ "\n\t" \
    "v_fmac_f32 v33, s" #SB ", v" #VZ "\n\t"
#define CH_B0_V40 \
    F2(36,52,40) F2(37,53,41) F2(38,54,42) F2(39,55,43) \
    F2(40,56,44) F2(41,57,45) F2(42,58,46) F2(43,59,47) \
    F2(44,60,48) F2(45,61,49) F2(46,62,50) F2(47,63,51) \
    F2(48,64,52) F2(49,65,53) F2(50,66,54) F2(51,67,55)
#define CH_B1_V56 \
    F2(68,84,56) F2(69,85,57) F2(70,86,58) F2(71,87,59) \
    F2(72,88,60) F2(73,89,61) F2(74,90,62) F2(75,91,63) \
    F2(76,92,64) F2(77,93,65) F2(78,94,66) F2(79,95,67) \
    F2(80,96,68) F2(81,97,69) F2(82,98,70) F2(83,99,71)
#define CH_B0_V72 \
    F2(36,52,72) F2(37,53,73) F2(38,54,74) F2(39,55,75) \
    F2(40,56,76) F2(41,57,77) F2(42,58,78) F2(43,59,79) \
    F2(44,60,80) F2(45,61,81) F2(46,62,82) F2(47,63,83) \
    F2(48,64,84) F2(49,65,85) F2(50,66,86) F2(51,67,87)
#define CH_B1_V88 \
    F2(68,84,88)  F2(69,85,89)  F2(70,86,90)  F2(71,87,91) \
    F2(72,88,92)  F2(73,89,93)  F2(74,90,94)  F2(75,91,95) \
    F2(76,92,96)  F2(77,93,97)  F2(78,94,98)  F2(79,95,99) \
    F2(80,96,100) F2(81,97,101) F2(82,98,102) F2(83,99,103)
// chunk loads: pair base s[34:35] = cb + h*64KB + pair*512B; k1 row at +0x100
#define LD_C0 \
    "s_load_dwordx16 s[36:51], s[34:35], 0x0\n\t" \
    "s_load_dwordx16 s[52:67], s[34:35], 0x100\n\t"
#define LD_C1 \
    "s_load_dwordx16 s[68:83], s[34:35], 0x40\n\t" \
    "s_load_dwordx16 s[84:99], s[34:35], 0x140\n\t"
#define LD_C2 \
    "s_load_dwordx16 s[36:51], s[34:35], 0x80\n\t" \
    "s_load_dwordx16 s[52:67], s[34:35], 0x180\n\t"
#define LD_C3 \
    "s_load_dwordx16 s[68:83], s[34:35], 0xC0\n\t" \
    "s_load_dwordx16 s[84:99], s[34:35], 0x1C0\n\t"
// per-pair tail: T = rn(s1+s2); d = rn(T-2M); per-lane argmin, k ascending,
// strict < (lowest k on ties). All cndmask operands VGPR (ISA-legal VOP2).
#define TAIL \
    "v_add_f32 v26, %[s1v], v22\n\t" \
    "v_add_f32 v27, %[s1v], v23\n\t" \
    "v_fma_f32 v26, v32, -2.0, v26\n\t" \
    "v_fma_f32 v27, v33, -2.0, v27\n\t" \
    "v_cmp_lt_f32 vcc, v26, v24\n\t" \
    "v_cndmask_b32 v24, v24, v26, vcc\n\t" \
    "v_cndmask_b32 v25, v25, v28, vcc\n\t" \
    "v_add_u32 v28, 1, v28\n\t" \
    "v_cmp_lt_f32 vcc, v27, v24\n\t" \
    "v_cndmask_b32 v24, v24, v27, vcc\n\t" \
    "v_cndmask_b32 v25, v25, v28, vcc\n\t" \
    "v_add_u32 v28, 1, v28\n\t" \
    "v_add_u32 v30, 8, v30\n\t"
// pair body head: the top lgkmcnt(0) drains exactly the chunk0 prefetch
// (issued during the previous pair's chunk3 compute + tail).
#define PAIR_HEAD \
    "s_waitcnt lgkmcnt(0)\n\t" \
    "v_mov_b32 v32, 0\n\t" \
    "v_mov_b32 v33, 0\n\t" \
    "ds_read_b64 v[22:23], v30\n\t" \
    LD_C1 \
    CH_B0_V40 \
    "s_waitcnt lgkmcnt(0)\n\t" \
    LD_C2 \
    CH_B1_V56 \
    "s_waitcnt lgkmcnt(0)\n\t" \
    LD_C3 \
    CH_B0_V72 \
    "s_waitcnt lgkmcnt(0)\n\t"

// ---------- kernel B: lane=sample, cb via scalar pipe, per-lane argmin ----------
__global__ __launch_bounds__(512, 4)
void vq23b(const float* __restrict__ cb,
           const float* __restrict__ zt,      // == ow (z_q region)
           const float* __restrict__ s1g,     // == ow + 8388608
           float* __restrict__ ow)
{
    __shared__ __align__(16) float s2l[512];
    __shared__ __align__(16) float md[2][256];    // per-half best d
    __shared__ __align__(16) int   mk[2][256];    // per-half best k
    __shared__ int   ifin[256];

    const int tid  = threadIdx.x;
    const int w    = tid >> 6;                // wave 0..7
    const int lane = tid & 63;
    const int g    = w & 3;                   // sample group (4 x 64 = 256)
    const int h    = w >> 2;                  // code half: 0 -> k 0..255, 1 -> 256..511
    const int n0   = blockIdx.x << 8;         // 512 blocks x 256 samples
    const int sloc = (g << 6) + lane;         // local sample
    const int n    = n0 + sloc;

    // ---- s2[tid] (np order: square->round, pairwise-8, no fma) — 1 code/thread ----
    {
        const float* row = cb + ((size_t)tid << 6);
        float q[8];
        #pragma unroll
        for (int j = 0; j < 8; ++j) q[j] = __fmul_rn(row[j], row[j]);
        #pragma unroll
        for (int m = 1; m < 8; ++m)
            #pragma unroll
            for (int j = 0; j < 8; ++j)
                q[j] = __fadd_rn(q[j], __fmul_rn(row[m*8+j], row[m*8+j]));
        s2l[tid] = __fadd_rn(__fadd_rn(__fadd_rn(q[0],q[1]),__fadd_rn(q[2],q[3])),
                             __fadd_rn(__fadd_rn(q[4],q[5]),__fadd_rn(q[6],q[7])));
    }

    const float  s1v = s1g[n];                     // read BEFORE overwrite
    const float* zp  = zt + ((size_t)n << 6);      // lane's z row (read in asm)
    const int    hof = h << 16;                    // half byte offset (wave-uniform)
    unsigned s2a = (unsigned)(unsigned long long)&s2l[h << 8];
    unsigned mda = (unsigned)(unsigned long long)&md[h][sloc];
    unsigned mka = (unsigned)(unsigned long long)&mk[h][sloc];
    const int k0i = h << 8;

    __syncthreads();   // s2l complete

    // ONE asm block: z load + cb stream + 128 code-pairs + result ds_writes.
    // (R18 lesson: no C++ between physical-reg definition and use.
    //  R22 lesson: "s" constraint only for provably-uniform values; the
    //  wave-uniform-but-divergent-in-analysis h offset goes via readfirstlane.)
    asm volatile(
        "v_readfirstlane_b32 s30, %[hof]\n\t"
        "s_add_u32 s34, %[cbp0], s30\n\t"          // pair base = cb + h*64KB
        "s_addc_u32 s35, %[cbp1], 0\n\t"
        "s_movk_i32 s33, 127\n\t"
        "v_mov_b32 v28, %[k0i]\n\t"                // running k index (VGPR)
        "v_mov_b32 v30, %[s2a]\n\t"
        "v_mov_b32 v24, 0x7f7fffff\n\t"            // best = FLT_MAX
        "v_mov_b32 v25, 0\n\t"                     // bi
        // lane's z row -> v[40:103] (once per 512-code scan)
        "global_load_dwordx4 v[40:43],  %[za], off\n\t"
        "global_load_dwordx4 v[44:47],  %[za], off offset:16\n\t"
        "global_load_dwordx4 v[48:51],  %[za], off offset:32\n\t"
        "global_load_dwordx4 v[52:55],  %[za], off offset:48\n\t"
        "global_load_dwordx4 v[56:59],  %[za], off offset:64\n\t"
        "global_load_dwordx4 v[60:63],  %[za], off offset:80\n\t"
        "global_load_dwordx4 v[64:67],  %[za], off offset:96\n\t"
        "global_load_dwordx4 v[68:71],  %[za], off offset:112\n\t"
        "global_load_dwordx4 v[72:75],  %[za], off offset:128\n\t"
        "global_load_dwordx4 v[76:79],  %[za], off offset:144\n\t"
        "global_load_dwordx4 v[80:83],  %[za], off offset:160\n\t"
        "global_load_dwordx4 v[84:87],  %[za], off offset:176\n\t"
        "global_load_dwordx4 v[88:91],  %[za], off offset:192\n\t"
        "global_load_dwordx4 v[92:95],  %[za], off offset:208\n\t"
        "global_load_dwordx4 v[96:99],  %[za], off offset:224\n\t"
        "global_load_dwordx4 v[100:103],%[za], off offset:240\n\t"
        LD_C0                                      // pair 0 chunk 0
        "s_waitcnt vmcnt(0)\n\t"                   // z resident
        // ---- 127 full pairs (with next-pair chunk0 prefetch) ----
        "1:\n\t"
        PAIR_HEAD
        "s_add_u32 s34, s34, 0x200\n\t"            // advance pair base (512B)
        "s_addc_u32 s35, s35, 0\n\t"
        LD_C0                                      // prefetch next pair chunk0
        CH_B1_V88
        TAIL
        "s_sub_i32 s33, s33, 1\n\t"
        "s_cmp_lg_u32 s33, 0\n\t"
        "s_cbranch_scc1 1b\n\t"
        // ---- peeled last pair (no prefetch: avoids cb overread) ----
        PAIR_HEAD
        CH_B1_V88
        TAIL
        // ---- per-lane result -> LDS ----
        "ds_write_b32 %[mda], v24\n\t"
        "ds_write_b32 %[mka], v25\n\t"
        : // no C++ outputs; results go through LDS
        : [cbp0] "s"((unsigned)(unsigned long long)cb),
          [cbp1] "s"((unsigned)((unsigned long long)cb >> 32)),
          [hof] "v"(hof), [k0i] "v"(k0i), [za] "v"(zp), [s1v] "v"(s1v),
          [s2a] "v"(s2a), [mda] "v"(mda), [mka] "v"(mka)
        : "memory", "vcc", "s30","s33","s34","s35",
          "s36","s37","s38","s39","s40","s41","s42","s43","s44","s45",
          "s46","s47","s48","s49","s50","s51","s52","s53","s54","s55",
          "s56","s57","s58","s59","s60","s61","s62","s63","s64","s65",
          "s66","s67","s68","s69","s70","s71","s72","s73","s74","s75",
          "s76","s77","s78","s79","s80","s81","s82","s83","s84","s85",
          "s86","s87","s88","s89","s90","s91","s92","s93","s94","s95",
          "s96","s97","s98","s99",
          "v22","v23","v24","v25","v26","v27","v28","v30","v32","v33",
          "v40","v41","v42","v43","v44","v45","v46","v47",
          "v48","v49","v50","v51","v52","v53","v54","v55",
          "v56","v57","v58","v59","v60","v61","v62","v63",
          "v64","v65","v66","v67","v68","v69","v70","v71",
          "v72","v73","v74","v75","v76","v77","v78","v79",
          "v80","v81","v82","v83","v84","v85","v86","v87",
          "v88","v89","v90","v91","v92","v93","v94","v95",
          "v96","v97","v98","v99","v100","v101","v102","v103");

    __syncthreads();   // md/mk complete; all zt/s1g reads done

    // ---- merge halves: h=0 first, strict < => lowest k on ties ----
    if (tid < 256) {
        float bd = md[0][tid]; int bk = mk[0][tid];
        const float d1 = md[1][tid];
        const int   k1 = mk[1][tid];
        if (d1 < bd) { bd = d1; bk = k1; }
        ifin[tid] = bk;
        ow[8388608 + n0 + tid] = (float)bk;        // overwrite s1 slice (safe)
    }
    __syncthreads();

    // ---- z_q gather: 256 samples x 64 floats, coalesced 16B stores ----
    float* ob = ow + ((size_t)n0 << 6);            // overwrite z_t slice (safe)
    #pragma unroll
    for (int it = 0; it < 8; ++it) {
        const int o    = it * 2048 + (tid << 2);   // float offset [0, 16384)
        const int sl   = o >> 6;
        const int c0   = o & 63;
        const int idx  = ifin[sl] & 511;
        const fl4 v = *(const fl4*)(cb + ((size_t)idx << 6) + c0);
        *(fl4*)(ob + o) = v;
    }
}

extern "C" void kernel_launch(void* const* d_in, const int* in_sizes, int n_in,
                              void* d_out, int out_size, void* d_ws, size_t ws_size,
                              hipStream_t stream) {
    const float* z  = (const float*)d_in[0];   // z_e fp32 [32,64,64,64]
    const float* cb = (const float*)d_in[1];   // codebook fp32 [512,64]
    float* out = (float*)d_out;                // fp32: z_q [8388608] ++ idx [131072]
    vq23a<<<512, 256, 0, stream>>>(z, out);
    vq23b<<<512, 512, 0, stream>>>(cb, out, out + 8388608, out);
}